// Round 6
// baseline (1964.797 us; speedup 1.0000x reference)
//
#include <hip/hip_runtime.h>

#define NNODES 50000
#define HDIM 256
#define NLAYERS 4
#define NEDGES 800000
#define FIN 1280
#define LDOUT 1024

typedef _Float16 f16;
typedef __attribute__((ext_vector_type(8))) _Float16 f16x8;
typedef __attribute__((ext_vector_type(4))) _Float16 f16x4;
typedef __attribute__((ext_vector_type(4))) float f32x4;

enum { SRC_F32 = 0, SRC_H = 1, SRC_MULH = 2, SRC_ADDRELU = 3, SRC_CATH = 4 };
enum { EPI_F16B = 0, EPI_W2W1 = 1, EPI_MASKXG = 2, EPI_CATH = 3 };

// ---------------------------------------------------------------------------
// Chunked MFMA GEMM: BM=64 x BN=256(per y-block), BK-chunk=256.
// 256 thr = 4 waves in 2x2: wave (wr,wc) owns rows wr*32+[0,32), cols
// wc*128+[0,128) (CFW=8).  Per 256-k chunk: stage 32KB A-tile to LDS with
// ROW-CONTIGUOUS global reads (thread t reads 64 consecutive k of one row),
// one barrier pair, then 4 k-tiles of MFMA with A from LDS and B fragments
// in registers (reloaded AFTER each MFMA cluster -> one tile of L2 slack).
// LDS slot map (16B units): u = tile*512 + (k_in_tile/8)*64 + row  — writes
// and reads both full-bandwidth (8-phase, distinct addresses per bank group).
// MFMA layouts (refcheck-validated R3-R5): A row=l&15(+16rf+32wr),
// k=(l>>4)*8+32kb; B col=l&15 (col-major Wt); C/D col=l&15,row=(l>>4)*4+j.
// ---------------------------------------------------------------------------
template<int SRC, int EPI, int KTILES>
__global__ __launch_bounds__(256) void mgemm_k(
    const float* __restrict__ A1, int lda1,     // esm / aggf
    const float* __restrict__ A2,               // maskb (MULH) / xw1 (ADDRELU)
    const float* __restrict__ sbias,            // b1 (ADDRELU)
    const f16*  __restrict__ A3,                // xh / agg2
    const f16*  __restrict__ A4,                // xh (CATH chunk 1)
    const f16*  __restrict__ Xh,                // xh (MASKXG epilogue)
    const f16*  __restrict__ Wt,                // [cols][K] col-major f16
    const float* __restrict__ bias,
    float* __restrict__ Cf, int ldc,
    f16*  __restrict__ Ch)
{
    constexpr int K = KTILES * 64;
    constexpr int CT = 4;                  // k-tiles per chunk (256 k)
    constexpr int NCH = KTILES / CT;
    __shared__ f16 Asm[CT * 512 * 8];      // 32 KB

    const int row0 = blockIdx.x * 64;
    const int by = blockIdx.y;
    const int tid = threadIdx.x;
    const int wv = tid >> 6;
    const int l = tid & 63;
    const int wr = wv >> 1, wc = wv & 1;

    // staging ids: thread covers row sr, 64 consecutive k (= one k-tile)
    const int sr = tid >> 2;               // 0..63
    const int lt = tid & 3;                // tile-in-chunk it stages
    const int grow = row0 + sr;
    const bool rok = grow < NNODES;

    // B per-lane base
    const int colg = by * 256 + wc * 128;
    const f16* bpB = Wt + (size_t)(colg + (l & 15)) * K + ((l >> 4) * 8);

    f32x4 acc[2][8] = {};
    f16x8 bfr[8][2];

    // preload B k-tile 0
    #pragma unroll
    for (int cf = 0; cf < 8; ++cf) {
        bfr[cf][0] = *(const f16x8*)(bpB + (size_t)cf * 16 * K);
        bfr[cf][1] = *(const f16x8*)(bpB + (size_t)cf * 16 * K + 32);
    }

    #pragma unroll
    for (int ch = 0; ch < NCH; ++ch) {
        if (ch > 0) __syncthreads();       // prev chunk's reads done
        // ---- stage chunk ch (rows row0..row0+63, k in [ch*256, ch*256+256))
        {
            const int kb0 = ch * 256 + lt * 64;
            const f16* srcp = nullptr;
            if constexpr (SRC == SRC_CATH) srcp = (ch == 0) ? A3 : A4;
            #pragma unroll 4
            for (int j = 0; j < 8; ++j) {
                const int k = kb0 + j * 8;
                f16x8 av;
                #pragma unroll
                for (int z = 0; z < 8; ++z) av[z] = (f16)0.f;
                if (rok) {
                    if constexpr (SRC == SRC_F32) {
                        const float* p = A1 + (size_t)grow * lda1 + k;
                        float4 v0 = *(const float4*)(p);
                        float4 v1 = *(const float4*)(p + 4);
                        av[0]=(f16)v0.x; av[1]=(f16)v0.y; av[2]=(f16)v0.z; av[3]=(f16)v0.w;
                        av[4]=(f16)v1.x; av[5]=(f16)v1.y; av[6]=(f16)v1.z; av[7]=(f16)v1.w;
                    } else if constexpr (SRC == SRC_H) {
                        av = *(const f16x8*)(A3 + (size_t)grow * HDIM + k);
                    } else if constexpr (SRC == SRC_MULH) {
                        f16x8 h = *(const f16x8*)(A3 + (size_t)grow * HDIM + k);
                        const float* m = A2 + (size_t)grow * HDIM + k;
                        float4 m0 = *(const float4*)(m);
                        float4 m1 = *(const float4*)(m + 4);
                        av[0]=(f16)((float)h[0]*m0.x); av[1]=(f16)((float)h[1]*m0.y);
                        av[2]=(f16)((float)h[2]*m0.z); av[3]=(f16)((float)h[3]*m0.w);
                        av[4]=(f16)((float)h[4]*m1.x); av[5]=(f16)((float)h[5]*m1.y);
                        av[6]=(f16)((float)h[6]*m1.z); av[7]=(f16)((float)h[7]*m1.w);
                    } else if constexpr (SRC == SRC_ADDRELU) {
                        const float* pa = A1 + (size_t)grow * HDIM + k;
                        const float* pb = A2 + (size_t)grow * HDIM + k;
                        const float* pc = sbias + k;
                        float4 a0 = *(const float4*)(pa), a1 = *(const float4*)(pa + 4);
                        float4 b0 = *(const float4*)(pb), b1 = *(const float4*)(pb + 4);
                        float4 c0 = *(const float4*)(pc), c1 = *(const float4*)(pc + 4);
                        av[0]=(f16)fmaxf(a0.x+b0.x+c0.x,0.f); av[1]=(f16)fmaxf(a0.y+b0.y+c0.y,0.f);
                        av[2]=(f16)fmaxf(a0.z+b0.z+c0.z,0.f); av[3]=(f16)fmaxf(a0.w+b0.w+c0.w,0.f);
                        av[4]=(f16)fmaxf(a1.x+b1.x+c1.x,0.f); av[5]=(f16)fmaxf(a1.y+b1.y+c1.y,0.f);
                        av[6]=(f16)fmaxf(a1.z+b1.z+c1.z,0.f); av[7]=(f16)fmaxf(a1.w+b1.w+c1.w,0.f);
                    } else { // SRC_CATH: chunk 0 from A3, chunk 1 from A4
                        av = *(const f16x8*)(srcp + (size_t)grow * HDIM + (k & 255));
                    }
                }
                // slot: tile lt, q=j, row sr
                *(f16x8*)(&Asm[(lt * 512 + j * 64 + sr) * 8]) = av;
            }
        }
        __syncthreads();

        // ---- compute CT k-tiles from LDS, B reg single-buffer issue-after
        #pragma unroll
        for (int it = 0; it < CT; ++it) {
            const int ktg = ch * CT + it;
            f16x8 af[2][2];
            #pragma unroll
            for (int rf = 0; rf < 2; ++rf)
                #pragma unroll
                for (int kb = 0; kb < 2; ++kb)
                    af[rf][kb] = *(const f16x8*)(&Asm[
                        (it * 512 + (kb * 4 + (l >> 4)) * 64
                         + wr * 32 + rf * 16 + (l & 15)) * 8]);
            #pragma unroll
            for (int cf = 0; cf < 8; ++cf)
                #pragma unroll
                for (int rf = 0; rf < 2; ++rf)
                    #pragma unroll
                    for (int kb = 0; kb < 2; ++kb)
                        acc[rf][cf] = __builtin_amdgcn_mfma_f32_16x16x32_f16(
                            af[rf][kb], bfr[cf][kb], acc[rf][cf], 0, 0, 0);
            if (ktg + 1 < KTILES) {
                #pragma unroll
                for (int cf = 0; cf < 8; ++cf) {
                    bfr[cf][0] = *(const f16x8*)(bpB + (size_t)cf * 16 * K + (ktg + 1) * 64);
                    bfr[cf][1] = *(const f16x8*)(bpB + (size_t)cf * 16 * K + (ktg + 1) * 64 + 32);
                }
            }
        }
    }

    // ---- epilogue
    #pragma unroll
    for (int rf = 0; rf < 2; ++rf) {
        #pragma unroll
        for (int jj = 0; jj < 4; ++jj) {
            const int row = row0 + wr * 32 + rf * 16 + (l >> 4) * 4 + jj;
            if (row >= NNODES) continue;
            #pragma unroll
            for (int cf = 0; cf < 8; ++cf) {
                const int col = wc * 128 + cf * 16 + (l & 15);
                float v = acc[rf][cf][jj];
                if constexpr (EPI == EPI_F16B) {
                    Ch[(size_t)row * HDIM + col] = (f16)(v + bias[col]);
                } else if constexpr (EPI == EPI_W2W1) {
                    if (by == 0) Ch[(size_t)row * HDIM + col] = (f16)(v + bias[col]);
                    else         Cf[(size_t)row * HDIM + col] = v;
                } else if constexpr (EPI == EPI_MASKXG) {
                    const float m = 1.f / (1.f + expf(-(v + bias[col])));
                    Cf[(size_t)row * HDIM + col] = m;
                    Ch[(size_t)row * HDIM + col] =
                        (f16)((float)Xh[(size_t)row * HDIM + col] * m);
                } else { // EPI_CATH
                    const float r = fmaxf(v + bias[col], 0.f);
                    Cf[(size_t)row * ldc + col] = r;
                    Ch[(size_t)row * HDIM + col] = (f16)r;
                }
            }
        }
    }
}

// ---------------------------------------------------------------------------
// weight pre-packs (f16 col-major)
// ---------------------------------------------------------------------------
__global__ __launch_bounds__(256) void pack_t_k(
    const float* __restrict__ W, f16* __restrict__ Wt, int K)
{
    const int idx = blockIdx.x * 256 + threadIdx.x;
    if (idx >= 256 * K) return;
    const int col = idx / K, k = idx % K;
    Wt[idx] = (f16)W[k * 256 + col];
}

// fused W2|W1: cols 0-255 -> W2, 256-511 -> W1, K=256
__global__ __launch_bounds__(256) void pack_w2w1_k(
    const float* __restrict__ W2, const float* __restrict__ W1,
    f16* __restrict__ Wt)
{
    const int idx = blockIdx.x * 256 + threadIdx.x;
    if (idx >= 512 * 256) return;
    const int col = idx / 256, k = idx % 256;
    Wt[idx] = (f16)(col < 256 ? W2[k * 256 + col] : W1[k * 256 + (col - 256)]);
}

// concat [Wn;Wr]: K=512
__global__ __launch_bounds__(256) void pack_cat_k(
    const float* __restrict__ Wn, const float* __restrict__ Wr,
    f16* __restrict__ Wt)
{
    const int idx = blockIdx.x * 256 + threadIdx.x;
    if (idx >= 256 * 512) return;
    const int col = idx / 512, k = idx % 512;
    Wt[idx] = (f16)(k < 256 ? Wn[k * 256 + col] : Wr[(k - 256) * 256 + col]);
}

// ---------------------------------------------------------------------------
// CSR build
// ---------------------------------------------------------------------------
__global__ __launch_bounds__(256) void count_k(
    const int* __restrict__ dstIdx, int* __restrict__ counts)
{
    const int e = blockIdx.x * 256 + threadIdx.x;
    if (e < NEDGES) atomicAdd(&counts[dstIdx[e]], 1);
}

__global__ __launch_bounds__(1024) void scan_k(
    const int* __restrict__ counts, int* __restrict__ starts)
{
    __shared__ int sm[1024];
    __shared__ int s_off;
    if (threadIdx.x == 0) s_off = 0;
    __syncthreads();
    for (int base = 0; base < NNODES; base += 1024) {
        const int i = base + threadIdx.x;
        const int v = (i < NNODES) ? counts[i] : 0;
        sm[threadIdx.x] = v;
        __syncthreads();
        for (int ofs = 1; ofs < 1024; ofs <<= 1) {
            const int t = (threadIdx.x >= ofs) ? sm[threadIdx.x - ofs] : 0;
            __syncthreads();
            sm[threadIdx.x] += t;
            __syncthreads();
        }
        const int incl = sm[threadIdx.x];
        const int off = s_off;
        if (i < NNODES) starts[i] = off + incl - v;
        __syncthreads();
        if (threadIdx.x == 1023) s_off = off + incl;
        __syncthreads();
    }
    if (threadIdx.x == 0) starts[NNODES] = s_off;
}

__global__ __launch_bounds__(256) void fillcsr_k(
    const int* __restrict__ srcIdx, const int* __restrict__ dstIdx,
    int* __restrict__ cursor, int* __restrict__ csr)
{
    const int e = blockIdx.x * 256 + threadIdx.x;
    if (e >= NEDGES) return;
    const int d = dstIdx[e];
    const int p = atomicAdd(&cursor[d], 1);
    csr[p] = srcIdx[e];
}

// ---------------------------------------------------------------------------
// gather-sums: one wave per node, unroll-4
// ---------------------------------------------------------------------------
__global__ __launch_bounds__(256) void gather_h_k(   // f16 -> f32
    const f16* __restrict__ rows, const int* __restrict__ csr,
    const int* __restrict__ starts, float* __restrict__ outp)
{
    const int node = (blockIdx.x * 256 + threadIdx.x) >> 6;
    const int lane = threadIdx.x & 63;
    if (node >= NNODES) return;
    const int e0 = starts[node], e1 = starts[node + 1];
    float a0=0,a1=0,a2=0,a3=0, b0=0,b1=0,b2=0,b3=0;
    int e = e0;
    for (; e + 3 < e1; e += 4) {
        const int s0=csr[e], s1=csr[e+1], s2=csr[e+2], s3=csr[e+3];
        f16x4 v0 = *(const f16x4*)(rows + (size_t)s0 * HDIM + lane * 4);
        f16x4 v1 = *(const f16x4*)(rows + (size_t)s1 * HDIM + lane * 4);
        f16x4 v2 = *(const f16x4*)(rows + (size_t)s2 * HDIM + lane * 4);
        f16x4 v3 = *(const f16x4*)(rows + (size_t)s3 * HDIM + lane * 4);
        a0 += (float)v0[0] + (float)v2[0]; a1 += (float)v0[1] + (float)v2[1];
        a2 += (float)v0[2] + (float)v2[2]; a3 += (float)v0[3] + (float)v2[3];
        b0 += (float)v1[0] + (float)v3[0]; b1 += (float)v1[1] + (float)v3[1];
        b2 += (float)v1[2] + (float)v3[2]; b3 += (float)v1[3] + (float)v3[3];
    }
    for (; e < e1; ++e) {
        const int s0 = csr[e];
        f16x4 v0 = *(const f16x4*)(rows + (size_t)s0 * HDIM + lane * 4);
        a0 += (float)v0[0]; a1 += (float)v0[1]; a2 += (float)v0[2]; a3 += (float)v0[3];
    }
    *(float4*)(outp + (size_t)node * HDIM + lane * 4) =
        make_float4(a0 + b0, a1 + b1, a2 + b2, a3 + b3);
}

__global__ __launch_bounds__(256) void gather_g_k(   // f16 -> f16
    const f16* __restrict__ rows, const int* __restrict__ csr,
    const int* __restrict__ starts, f16* __restrict__ outp)
{
    const int node = (blockIdx.x * 256 + threadIdx.x) >> 6;
    const int lane = threadIdx.x & 63;
    if (node >= NNODES) return;
    const int e0 = starts[node], e1 = starts[node + 1];
    float a0=0,a1=0,a2=0,a3=0, b0=0,b1=0,b2=0,b3=0;
    int e = e0;
    for (; e + 3 < e1; e += 4) {
        const int s0=csr[e], s1=csr[e+1], s2=csr[e+2], s3=csr[e+3];
        f16x4 v0 = *(const f16x4*)(rows + (size_t)s0 * HDIM + lane * 4);
        f16x4 v1 = *(const f16x4*)(rows + (size_t)s1 * HDIM + lane * 4);
        f16x4 v2 = *(const f16x4*)(rows + (size_t)s2 * HDIM + lane * 4);
        f16x4 v3 = *(const f16x4*)(rows + (size_t)s3 * HDIM + lane * 4);
        a0 += (float)v0[0] + (float)v2[0]; a1 += (float)v0[1] + (float)v2[1];
        a2 += (float)v0[2] + (float)v2[2]; a3 += (float)v0[3] + (float)v2[3];
        b0 += (float)v1[0] + (float)v3[0]; b1 += (float)v1[1] + (float)v3[1];
        b2 += (float)v1[2] + (float)v3[2]; b3 += (float)v1[3] + (float)v3[3];
    }
    for (; e < e1; ++e) {
        const int s0 = csr[e];
        f16x4 v0 = *(const f16x4*)(rows + (size_t)s0 * HDIM + lane * 4);
        a0 += (float)v0[0]; a1 += (float)v0[1]; a2 += (float)v0[2]; a3 += (float)v0[3];
    }
    f16x4 r;
    r[0] = (f16)(a0 + b0); r[1] = (f16)(a1 + b1);
    r[2] = (f16)(a2 + b2); r[3] = (f16)(a3 + b3);
    *(f16x4*)(outp + (size_t)node * HDIM + lane * 4) = r;
}

__global__ __launch_bounds__(256) void fill1_k(float* __restrict__ p, int n)
{
    const int t = blockIdx.x * 256 + threadIdx.x;
    if (t < n) p[t] = 1.0f;
}

// ---------------------------------------------------------------------------
extern "C" void kernel_launch(void* const* d_in, const int* in_sizes, int n_in,
                              void* d_out, int out_size, void* d_ws, size_t ws_size,
                              hipStream_t stream)
{
    const int*   edge   = (const int*)d_in[1];
    const int*   src    = edge;
    const int*   dst    = edge + NEDGES;
    const float* esm    = (const float*)d_in[2];
    const float* lin0_W = (const float*)d_in[4];
    const float* lin0_b = (const float*)d_in[5];
    const float* wc_W1  = (const float*)d_in[6];
    const float* wc_b1  = (const float*)d_in[7];
    const float* wc_W2  = (const float*)d_in[8];
    const float* wc_b2  = (const float*)d_in[9];
    const float* wc_W3  = (const float*)d_in[10];
    const float* wc_b3  = (const float*)d_in[11];
    const float* sc_Wn  = (const float*)d_in[12];
    const float* sc_bn  = (const float*)d_in[13];
    const float* sc_Wr  = (const float*)d_in[14];
    float* out = (float*)d_out;

    const size_t NH = (size_t)NNODES * HDIM;
    float* ws    = (float*)d_ws;
    float* aggf  = ws;                    // f32 [N,256]
    float* xw1   = ws + NH;               // f32 [N,256]
    float* maskb = ws + 2 * NH;           // f32 [N,256]
    f16*   xh    = (f16*)(ws + 3 * NH);   // f16 [N,256]  (current x)
    f16*   hnb   = xh + NH;               // f16 [N,256]  (h_nb, then xg)
    f16*   agg2  = hnb + NH;              // f16 [N,256]
    f16*   lin0t = agg2 + NH;             // 256*1280
    f16*   WF    = lin0t + 256 * FIN;     // fused W2|W1: 4 * 131072
    f16*   W3t   = WF + 4 * 131072;       // 4 * 65536
    f16*   WtC   = W3t + 4 * 65536;       // 4 * 131072
    int*   iws    = (int*)(WtC + 4 * 131072);
    int*   counts = iws;
    int*   starts = iws + NNODES;
    int*   cursor = iws + 2 * NNODES + 1;
    int*   csr    = iws + 3 * NNODES + 2;

    const dim3 blk(256);
    const int gemmGrid = (NNODES + 63) / 64;           // 782
    const int edgeGrid = (NEDGES + 255) / 256;
    const int waveGrid = (NNODES * 64) / 256;

    // ---- CSR build
    hipMemsetAsync(counts, 0, NNODES * sizeof(int), stream);
    count_k<<<edgeGrid, blk, 0, stream>>>(dst, counts);
    scan_k<<<1, 1024, 0, stream>>>(counts, starts);
    hipMemcpyAsync(cursor, starts, NNODES * sizeof(int),
                   hipMemcpyDeviceToDevice, stream);
    fillcsr_k<<<edgeGrid, blk, 0, stream>>>(src, dst, cursor, csr);

    // ---- weight packs
    pack_t_k<<<(256 * FIN + 255) / 256, blk, 0, stream>>>(lin0_W, lin0t, FIN);
    for (int i = 0; i < NLAYERS; ++i) {
        const size_t wo = (size_t)i * HDIM * HDIM;
        pack_w2w1_k<<<512, blk, 0, stream>>>(wc_W2 + wo, wc_W1 + wo, WF + i * 131072);
        pack_t_k<<<256, blk, 0, stream>>>(wc_W3 + wo, W3t + i * 65536, 256);
        pack_cat_k<<<512, blk, 0, stream>>>(sc_Wn + wo, sc_Wr + wo, WtC + i * 131072);
    }

    // ---- lin0: xh = f16(esm @ W + b)
    mgemm_k<SRC_F32, EPI_F16B, FIN / 64><<<gemmGrid, blk, 0, stream>>>(
        esm, FIN, nullptr, nullptr, nullptr, nullptr, nullptr, lin0t, lin0_b,
        nullptr, 0, xh);

    for (int i = 0; i < NLAYERS; ++i) {
        const size_t bo = (size_t)i * HDIM;
        const f16* wf = WF + i * 131072;
        const f16* w3 = W3t + i * 65536;
        const f16* wc = WtC + i * 131072;

        // fused (grid.y=2): y0: hnb = xm@W2+b2 (f16);  y1: xw1 = xm@W1 (f32)
        if (i == 0) {
            mgemm_k<SRC_H, EPI_W2W1, 4><<<dim3(gemmGrid, 2), blk, 0, stream>>>(
                nullptr, 0, nullptr, nullptr, xh, nullptr, nullptr, wf, wc_b2 + bo,
                xw1, HDIM, hnb);
        } else {
            mgemm_k<SRC_MULH, EPI_W2W1, 4><<<dim3(gemmGrid, 2), blk, 0, stream>>>(
                nullptr, 0, maskb, nullptr, xh, nullptr, nullptr, wf, wc_b2 + bo,
                xw1, HDIM, hnb);
        }
        // agg = segment_sum(h_nb[src], dst)
        gather_h_k<<<waveGrid, blk, 0, stream>>>(hnb, csr, starts, aggf);
        // mask = sigmoid( relu(agg + xw1 + b1) @ W3 + b3 ); xg = xh*mask (fused)
        mgemm_k<SRC_ADDRELU, EPI_MASKXG, 4><<<gemmGrid, blk, 0, stream>>>(
            aggf, HDIM, xw1, wc_b1 + bo, nullptr, nullptr, xh, w3, wc_b3 + bo,
            maskb, HDIM, hnb);
        // agg2 = segment_sum(xg[src], dst)
        gather_g_k<<<waveGrid, blk, 0, stream>>>(hnb, csr, starts, agg2);
        // x_new = relu([agg2 | xh] @ [Wn;Wr] + bn) -> d_out slice i (+ xh f16)
        mgemm_k<SRC_CATH, EPI_CATH, 8><<<gemmGrid, blk, 0, stream>>>(
            nullptr, 0, nullptr, nullptr, agg2, xh, nullptr, wc, sc_bn + bo,
            out + (size_t)i * HDIM, LDOUT, xh);
    }

    // node_mask: all true
    const size_t maskOff = (size_t)NNODES * LDOUT;
    fill1_k<<<(NNODES + 255) / 256, blk, 0, stream>>>(out + maskOff, NNODES);
}

// Round 7
// 1437.053 us; speedup vs baseline: 1.3672x; 1.3672x over previous
//
#include <hip/hip_runtime.h>

#define NNODES 50000
#define HDIM 256
#define NLAYERS 4
#define NEDGES 800000
#define FIN 1280
#define LDOUT 1024

typedef _Float16 f16;
typedef __attribute__((ext_vector_type(8))) _Float16 f16x8;
typedef __attribute__((ext_vector_type(4))) _Float16 f16x4;
typedef __attribute__((ext_vector_type(4))) float f32x4;

enum { SRC_F32Y = 0, SRC_H = 1, SRC_MULH = 2, SRC_ADDRELU_H = 3, SRC_CATH = 4 };
enum { EPI_PART = 0, EPI_W2W1H = 1, EPI_MASKXG = 2, EPI_CATH = 3 };

// ---------------------------------------------------------------------------
// Pipelined MFMA GEMM (R4 structure + depth-2 reg prefetch + y-multiplex):
// BM=64 x BN=256, BK=64, 256 thr = 4 waves (wave wv owns cols wv*64..+64).
// Double-buffered LDS A-tile; TWO named staging reg-sets (RA/RB) so loads for
// tile t+2 are issued while tile t computes (static indexing, loop unrolled x2).
// by (blockIdx.y) multiplexes: lin0 K-halves (SRC_F32Y / EPI_PART) and the
// W2|W1 pair (EPI_W2W1H).  MFMA layouts refcheck-validated R3-R6:
// A row=l&15, k=(l>>4)*8+j (+32kb); B col=l&15 (col-major Wt);
// C/D col=l&15, row=(l>>4)*4+reg.
// ---------------------------------------------------------------------------
template<int SRC, int EPI, int KTILES>
__global__ __launch_bounds__(256) void mgemm_k(
    const float* __restrict__ A1, int lda1,   // esm (F32Y) / aggf (ADDRELU_H)
    const f16*  __restrict__ A3,              // xh / agg2
    const f16*  __restrict__ A5,              // maskh (MULH) / xw1h (ADDRELU_H)
    const f16*  __restrict__ A4,              // xh (CATH k>=256)
    const f16*  __restrict__ Xh,              // xh (MASKXG epilogue)
    const f16*  __restrict__ Wt,              // [256 cols][K] col-major f16
    const f16*  __restrict__ Wt2,             // y=1 weight (or ==Wt)
    const float* __restrict__ bias,
    const float* __restrict__ bias2,
    float* __restrict__ Cf, int ldc,
    float* __restrict__ Cf2,
    f16*  __restrict__ Ch,
    f16*  __restrict__ Ch2)
{
    constexpr int K = KTILES * 64;
    __shared__ f16 Asm[2][4096];              // 2 x 8 KB

    const int row0 = blockIdx.x * 64;
    const int by = blockIdx.y;
    const int tid = threadIdx.x;
    const int wv = tid >> 6;
    const int l = tid & 63;

    f32x4 acc[4][4] = {};

    // staging: thread t -> row sr=t>>2, k-cols [sc0, sc0+16)
    const int sr = tid >> 2;
    const int sc0 = (tid & 3) * 16;
    const int grow = row0 + sr;
    const bool rok = grow < NNODES;
    const int kg = (SRC == SRC_F32Y) ? by * K : 0;    // lin0 K-half offset
    const int lane_base0 =
        (((sc0 >> 5) * 4 + (sr >> 4)) * 64 + (sr & 15) + (((sc0 & 31) >> 3) * 16)) * 8;
    const int lane_base1 = lane_base0 + 128;

    const f16* Wsel = by ? Wt2 : Wt;
    const f16* bp[4];
    #pragma unroll
    for (int cf = 0; cf < 4; ++cf)
        bp[cf] = Wsel + (size_t)(wv * 64 + cf * 16 + (l & 15)) * K + ((l >> 4) * 8);

    struct SReg { float4 f0, f1, f2, f3; f16x8 h0, h1, g0, g1; };
    SReg RA, RB;

    auto LOAD = [&](SReg& r, int kt) {
        if (!rok) return;
        const int k0 = kt * 64 + sc0;
        if constexpr (SRC == SRC_F32Y) {
            const float* p = A1 + (size_t)grow * lda1 + kg + k0;
            r.f0 = *(const float4*)(p + 0);  r.f1 = *(const float4*)(p + 4);
            r.f2 = *(const float4*)(p + 8);  r.f3 = *(const float4*)(p + 12);
        } else if constexpr (SRC == SRC_H) {
            const f16* p = A3 + (size_t)grow * HDIM + k0;
            r.h0 = *(const f16x8*)p;  r.h1 = *(const f16x8*)(p + 8);
        } else if constexpr (SRC == SRC_MULH) {
            const f16* p = A3 + (size_t)grow * HDIM + k0;
            const f16* q = A5 + (size_t)grow * HDIM + k0;
            r.h0 = *(const f16x8*)p;  r.h1 = *(const f16x8*)(p + 8);
            r.g0 = *(const f16x8*)q;  r.g1 = *(const f16x8*)(q + 8);
        } else if constexpr (SRC == SRC_ADDRELU_H) {
            const float* p = A1 + (size_t)grow * HDIM + k0;
            const f16* q = A5 + (size_t)grow * HDIM + k0;
            r.f0 = *(const float4*)(p + 0);  r.f1 = *(const float4*)(p + 4);
            r.f2 = *(const float4*)(p + 8);  r.f3 = *(const float4*)(p + 12);
            r.h0 = *(const f16x8*)q;  r.h1 = *(const f16x8*)(q + 8);
        } else { // SRC_CATH
            const f16* p = (k0 < HDIM)
                ? (A3 + (size_t)grow * HDIM + k0)
                : (A4 + (size_t)grow * HDIM + (k0 - HDIM));
            r.h0 = *(const f16x8*)p;  r.h1 = *(const f16x8*)(p + 8);
        }
    };

    auto COMMIT = [&](const SReg& r, int b) {
        f16x8 av0, av1;
        #pragma unroll
        for (int i = 0; i < 8; ++i) { av0[i] = (f16)0.f; av1[i] = (f16)0.f; }
        if (rok) {
            if constexpr (SRC == SRC_F32Y) {
                av0[0]=(f16)r.f0.x; av0[1]=(f16)r.f0.y; av0[2]=(f16)r.f0.z; av0[3]=(f16)r.f0.w;
                av0[4]=(f16)r.f1.x; av0[5]=(f16)r.f1.y; av0[6]=(f16)r.f1.z; av0[7]=(f16)r.f1.w;
                av1[0]=(f16)r.f2.x; av1[1]=(f16)r.f2.y; av1[2]=(f16)r.f2.z; av1[3]=(f16)r.f2.w;
                av1[4]=(f16)r.f3.x; av1[5]=(f16)r.f3.y; av1[6]=(f16)r.f3.z; av1[7]=(f16)r.f3.w;
            } else if constexpr (SRC == SRC_H || SRC == SRC_CATH) {
                av0 = r.h0; av1 = r.h1;
            } else if constexpr (SRC == SRC_MULH) {
                #pragma unroll
                for (int i = 0; i < 8; ++i) {
                    av0[i] = (f16)((float)r.h0[i] * (float)r.g0[i]);
                    av1[i] = (f16)((float)r.h1[i] * (float)r.g1[i]);
                }
            } else if constexpr (SRC == SRC_ADDRELU_H) {
                av0[0]=(f16)fmaxf(r.f0.x+(float)r.h0[0],0.f); av0[1]=(f16)fmaxf(r.f0.y+(float)r.h0[1],0.f);
                av0[2]=(f16)fmaxf(r.f0.z+(float)r.h0[2],0.f); av0[3]=(f16)fmaxf(r.f0.w+(float)r.h0[3],0.f);
                av0[4]=(f16)fmaxf(r.f1.x+(float)r.h0[4],0.f); av0[5]=(f16)fmaxf(r.f1.y+(float)r.h0[5],0.f);
                av0[6]=(f16)fmaxf(r.f1.z+(float)r.h0[6],0.f); av0[7]=(f16)fmaxf(r.f1.w+(float)r.h0[7],0.f);
                av1[0]=(f16)fmaxf(r.f2.x+(float)r.h1[0],0.f); av1[1]=(f16)fmaxf(r.f2.y+(float)r.h1[1],0.f);
                av1[2]=(f16)fmaxf(r.f2.z+(float)r.h1[2],0.f); av1[3]=(f16)fmaxf(r.f2.w+(float)r.h1[3],0.f);
                av1[4]=(f16)fmaxf(r.f3.x+(float)r.h1[4],0.f); av1[5]=(f16)fmaxf(r.f3.y+(float)r.h1[5],0.f);
                av1[6]=(f16)fmaxf(r.f3.z+(float)r.h1[6],0.f); av1[7]=(f16)fmaxf(r.f3.w+(float)r.h1[7],0.f);
            }
        }
        *(f16x8*)(&Asm[b][lane_base0]) = av0;
        *(f16x8*)(&Asm[b][lane_base1]) = av1;
    };

    auto TILE = [&](int b, int kt) {
        f16x8 af[4][2];
        #pragma unroll
        for (int rf = 0; rf < 4; ++rf)
            #pragma unroll
            for (int kb = 0; kb < 2; ++kb)
                af[rf][kb] = *(const f16x8*)(&Asm[b][((kb * 4 + rf) * 64 + l) * 8]);
        f16x8 bfr[4][2];
        #pragma unroll
        for (int cf = 0; cf < 4; ++cf) {
            bfr[cf][0] = *(const f16x8*)(bp[cf] + kt * 64);
            bfr[cf][1] = *(const f16x8*)(bp[cf] + kt * 64 + 32);
        }
        #pragma unroll
        for (int cf = 0; cf < 4; ++cf)
            #pragma unroll
            for (int rf = 0; rf < 4; ++rf)
                #pragma unroll
                for (int kb = 0; kb < 2; ++kb)
                    acc[rf][cf] = __builtin_amdgcn_mfma_f32_16x16x32_f16(
                        af[rf][kb], bfr[cf][kb], acc[rf][cf], 0, 0, 0);
    };

    // depth-2 pipeline: loads for tile t+2 in flight while tile t computes
    LOAD(RA, 0);
    COMMIT(RA, 0);
    if (KTILES > 1) LOAD(RB, 1);
    #pragma unroll
    for (int kt2 = 0; kt2 < KTILES; kt2 += 2) {
        __syncthreads();
        TILE(0, kt2);
        if (kt2 + 1 < KTILES) COMMIT(RB, 1);
        if (kt2 + 2 < KTILES) LOAD(RA, kt2 + 2);
        if (kt2 + 1 < KTILES) {
            __syncthreads();
            TILE(1, kt2 + 1);
            if (kt2 + 2 < KTILES) COMMIT(RA, 0);
            if (kt2 + 3 < KTILES) LOAD(RB, kt2 + 3);
        }
    }

    // ---- epilogue
    #pragma unroll
    for (int rf = 0; rf < 4; ++rf) {
        #pragma unroll
        for (int j = 0; j < 4; ++j) {
            const int row = row0 + rf * 16 + ((l >> 4) * 4) + j;
            if (row >= NNODES) continue;
            #pragma unroll
            for (int cf = 0; cf < 4; ++cf) {
                const int col = wv * 64 + cf * 16 + (l & 15);
                float v = acc[rf][cf][j];
                if constexpr (EPI == EPI_PART) {
                    (by ? Cf2 : Cf)[(size_t)row * HDIM + col] = v;
                } else if constexpr (EPI == EPI_W2W1H) {
                    if (by == 0) Ch[(size_t)row * HDIM + col]  = (f16)(v + bias[col]);
                    else         Ch2[(size_t)row * HDIM + col] = (f16)(v + bias2[col]);
                } else if constexpr (EPI == EPI_MASKXG) {
                    const float m = 1.f / (1.f + expf(-(v + bias[col])));
                    Ch2[(size_t)row * HDIM + col] = (f16)m;
                    Ch[(size_t)row * HDIM + col] =
                        (f16)((float)Xh[(size_t)row * HDIM + col] * m);
                } else { // EPI_CATH
                    const float r = fmaxf(v + bias[col], 0.f);
                    Cf[(size_t)row * ldc + col] = r;
                    Ch[(size_t)row * HDIM + col] = (f16)r;
                }
            }
        }
    }
}

// ---------------------------------------------------------------------------
// combine: xh = f16(P0 + P1 + b)
// ---------------------------------------------------------------------------
__global__ __launch_bounds__(256) void combine_k(
    const float* __restrict__ P0, const float* __restrict__ P1,
    const float* __restrict__ b, f16* __restrict__ xh)
{
    const int t = blockIdx.x * 256 + threadIdx.x;
    const int row = t >> 6;
    const int c = (t & 63) * 4;
    if (row >= NNODES) return;
    const float4 a = *(const float4*)(P0 + (size_t)row * HDIM + c);
    const float4 d = *(const float4*)(P1 + (size_t)row * HDIM + c);
    const float4 bb = *(const float4*)(b + c);
    f16x4 r;
    r[0] = (f16)(a.x + d.x + bb.x); r[1] = (f16)(a.y + d.y + bb.y);
    r[2] = (f16)(a.z + d.z + bb.z); r[3] = (f16)(a.w + d.w + bb.w);
    *(f16x4*)(xh + (size_t)row * HDIM + c) = r;
}

// ---------------------------------------------------------------------------
// weight pre-packs (f16 col-major): Wt[col][k] <- W[k][col], 256 cols
// ---------------------------------------------------------------------------
__global__ __launch_bounds__(256) void pack_t_k(
    const float* __restrict__ W, f16* __restrict__ Wt, int K)
{
    const int idx = blockIdx.x * 256 + threadIdx.x;
    if (idx >= 256 * K) return;
    const int col = idx / K, k = idx % K;
    Wt[idx] = (f16)W[k * 256 + col];
}

// concat [Wn;Wr]: K=512
__global__ __launch_bounds__(256) void pack_cat_k(
    const float* __restrict__ Wn, const float* __restrict__ Wr,
    f16* __restrict__ Wt)
{
    const int idx = blockIdx.x * 256 + threadIdx.x;
    if (idx >= 256 * 512) return;
    const int col = idx / 512, k = idx % 512;
    Wt[idx] = (f16)(k < 256 ? Wn[k * 256 + col] : Wr[(k - 256) * 256 + col]);
}

// ---------------------------------------------------------------------------
// CSR build
// ---------------------------------------------------------------------------
__global__ __launch_bounds__(256) void count_k(
    const int* __restrict__ dstIdx, int* __restrict__ counts)
{
    const int e = blockIdx.x * 256 + threadIdx.x;
    if (e < NEDGES) atomicAdd(&counts[dstIdx[e]], 1);
}

__global__ __launch_bounds__(1024) void scan_k(
    const int* __restrict__ counts, int* __restrict__ starts)
{
    __shared__ int sm[1024];
    __shared__ int s_off;
    if (threadIdx.x == 0) s_off = 0;
    __syncthreads();
    for (int base = 0; base < NNODES; base += 1024) {
        const int i = base + threadIdx.x;
        const int v = (i < NNODES) ? counts[i] : 0;
        sm[threadIdx.x] = v;
        __syncthreads();
        for (int ofs = 1; ofs < 1024; ofs <<= 1) {
            const int t = (threadIdx.x >= ofs) ? sm[threadIdx.x - ofs] : 0;
            __syncthreads();
            sm[threadIdx.x] += t;
            __syncthreads();
        }
        const int incl = sm[threadIdx.x];
        const int off = s_off;
        if (i < NNODES) starts[i] = off + incl - v;
        __syncthreads();
        if (threadIdx.x == 1023) s_off = off + incl;
        __syncthreads();
    }
    if (threadIdx.x == 0) starts[NNODES] = s_off;
}

__global__ __launch_bounds__(256) void fillcsr_k(
    const int* __restrict__ srcIdx, const int* __restrict__ dstIdx,
    int* __restrict__ cursor, int* __restrict__ csr)
{
    const int e = blockIdx.x * 256 + threadIdx.x;
    if (e >= NEDGES) return;
    const int d = dstIdx[e];
    const int p = atomicAdd(&cursor[d], 1);
    csr[p] = srcIdx[e];
}

// ---------------------------------------------------------------------------
// gather-sums: one wave per node, unroll-4
// ---------------------------------------------------------------------------
__global__ __launch_bounds__(256) void gather_h_k(   // f16 -> f32
    const f16* __restrict__ rows, const int* __restrict__ csr,
    const int* __restrict__ starts, float* __restrict__ outp)
{
    const int node = (blockIdx.x * 256 + threadIdx.x) >> 6;
    const int lane = threadIdx.x & 63;
    if (node >= NNODES) return;
    const int e0 = starts[node], e1 = starts[node + 1];
    float a0=0,a1=0,a2=0,a3=0, b0=0,b1=0,b2=0,b3=0;
    int e = e0;
    for (; e + 3 < e1; e += 4) {
        const int s0=csr[e], s1=csr[e+1], s2=csr[e+2], s3=csr[e+3];
        f16x4 v0 = *(const f16x4*)(rows + (size_t)s0 * HDIM + lane * 4);
        f16x4 v1 = *(const f16x4*)(rows + (size_t)s1 * HDIM + lane * 4);
        f16x4 v2 = *(const f16x4*)(rows + (size_t)s2 * HDIM + lane * 4);
        f16x4 v3 = *(const f16x4*)(rows + (size_t)s3 * HDIM + lane * 4);
        a0 += (float)v0[0] + (float)v2[0]; a1 += (float)v0[1] + (float)v2[1];
        a2 += (float)v0[2] + (float)v2[2]; a3 += (float)v0[3] + (float)v2[3];
        b0 += (float)v1[0] + (float)v3[0]; b1 += (float)v1[1] + (float)v3[1];
        b2 += (float)v1[2] + (float)v3[2]; b3 += (float)v1[3] + (float)v3[3];
    }
    for (; e < e1; ++e) {
        const int s0 = csr[e];
        f16x4 v0 = *(const f16x4*)(rows + (size_t)s0 * HDIM + lane * 4);
        a0 += (float)v0[0]; a1 += (float)v0[1]; a2 += (float)v0[2]; a3 += (float)v0[3];
    }
    *(float4*)(outp + (size_t)node * HDIM + lane * 4) =
        make_float4(a0 + b0, a1 + b1, a2 + b2, a3 + b3);
}

__global__ __launch_bounds__(256) void gather_g_k(   // f16 -> f16
    const f16* __restrict__ rows, const int* __restrict__ csr,
    const int* __restrict__ starts, f16* __restrict__ outp)
{
    const int node = (blockIdx.x * 256 + threadIdx.x) >> 6;
    const int lane = threadIdx.x & 63;
    if (node >= NNODES) return;
    const int e0 = starts[node], e1 = starts[node + 1];
    float a0=0,a1=0,a2=0,a3=0, b0=0,b1=0,b2=0,b3=0;
    int e = e0;
    for (; e + 3 < e1; e += 4) {
        const int s0=csr[e], s1=csr[e+1], s2=csr[e+2], s3=csr[e+3];
        f16x4 v0 = *(const f16x4*)(rows + (size_t)s0 * HDIM + lane * 4);
        f16x4 v1 = *(const f16x4*)(rows + (size_t)s1 * HDIM + lane * 4);
        f16x4 v2 = *(const f16x4*)(rows + (size_t)s2 * HDIM + lane * 4);
        f16x4 v3 = *(const f16x4*)(rows + (size_t)s3 * HDIM + lane * 4);
        a0 += (float)v0[0] + (float)v2[0]; a1 += (float)v0[1] + (float)v2[1];
        a2 += (float)v0[2] + (float)v2[2]; a3 += (float)v0[3] + (float)v2[3];
        b0 += (float)v1[0] + (float)v3[0]; b1 += (float)v1[1] + (float)v3[1];
        b2 += (float)v1[2] + (float)v3[2]; b3 += (float)v1[3] + (float)v3[3];
    }
    for (; e < e1; ++e) {
        const int s0 = csr[e];
        f16x4 v0 = *(const f16x4*)(rows + (size_t)s0 * HDIM + lane * 4);
        a0 += (float)v0[0]; a1 += (float)v0[1]; a2 += (float)v0[2]; a3 += (float)v0[3];
    }
    f16x4 r;
    r[0] = (f16)(a0 + b0); r[1] = (f16)(a1 + b1);
    r[2] = (f16)(a2 + b2); r[3] = (f16)(a3 + b3);
    *(f16x4*)(outp + (size_t)node * HDIM + lane * 4) = r;
}

__global__ __launch_bounds__(256) void fill1_k(float* __restrict__ p, int n)
{
    const int t = blockIdx.x * 256 + threadIdx.x;
    if (t < n) p[t] = 1.0f;
}

// ---------------------------------------------------------------------------
extern "C" void kernel_launch(void* const* d_in, const int* in_sizes, int n_in,
                              void* d_out, int out_size, void* d_ws, size_t ws_size,
                              hipStream_t stream)
{
    const int*   edge   = (const int*)d_in[1];
    const int*   src    = edge;
    const int*   dst    = edge + NEDGES;
    const float* esm    = (const float*)d_in[2];
    const float* lin0_W = (const float*)d_in[4];
    const float* lin0_b = (const float*)d_in[5];
    const float* wc_W1  = (const float*)d_in[6];
    const float* wc_b1  = (const float*)d_in[7];
    const float* wc_W2  = (const float*)d_in[8];
    const float* wc_b2  = (const float*)d_in[9];
    const float* wc_W3  = (const float*)d_in[10];
    const float* wc_b3  = (const float*)d_in[11];
    const float* sc_Wn  = (const float*)d_in[12];
    const float* sc_bn  = (const float*)d_in[13];
    const float* sc_Wr  = (const float*)d_in[14];
    float* out = (float*)d_out;

    const size_t NH = (size_t)NNODES * HDIM;
    float* ws    = (float*)d_ws;
    float* aggf  = ws;                    // f32 [N,256]  (also lin0 partial P0)
    float* part1 = ws + NH;               // f32 [N,256]  (lin0 partial P1)
    f16*   xh    = (f16*)(ws + 2 * NH);   // f16 [N,256]  current x
    f16*   hnb   = xh + NH;               // f16 [N,256]  h_nb, then xg
    f16*   agg2  = hnb + NH;              // f16 [N,256]
    f16*   xw1h  = agg2 + NH;             // f16 [N,256]  xm@W1 + b1
    f16*   maskh = xw1h + NH;             // f16 [N,256]
    f16*   lin0tA = maskh + NH;           // 256*640
    f16*   lin0tB = lin0tA + 256 * 640;   // 256*640
    f16*   W2t   = lin0tB + 256 * 640;    // 4 * 65536
    f16*   W1t   = W2t + 4 * 65536;
    f16*   W3t   = W1t + 4 * 65536;
    f16*   WtC   = W3t + 4 * 65536;       // 4 * 131072
    int*   iws    = (int*)(WtC + 4 * 131072);
    int*   counts = iws;
    int*   starts = iws + NNODES;
    int*   cursor = iws + 2 * NNODES + 1;
    int*   csr    = iws + 3 * NNODES + 2;

    const dim3 blk(256);
    const int gemmGrid = (NNODES + 63) / 64;           // 782
    const int edgeGrid = (NEDGES + 255) / 256;
    const int waveGrid = (NNODES * 64) / 256;

    // ---- CSR build
    hipMemsetAsync(counts, 0, NNODES * sizeof(int), stream);
    count_k<<<edgeGrid, blk, 0, stream>>>(dst, counts);
    scan_k<<<1, 1024, 0, stream>>>(counts, starts);
    hipMemcpyAsync(cursor, starts, NNODES * sizeof(int),
                   hipMemcpyDeviceToDevice, stream);
    fillcsr_k<<<edgeGrid, blk, 0, stream>>>(src, dst, cursor, csr);

    // ---- weight packs
    pack_t_k<<<640, blk, 0, stream>>>(lin0_W, lin0tA, 640);
    pack_t_k<<<640, blk, 0, stream>>>(lin0_W + 640 * 256, lin0tB, 640);
    for (int i = 0; i < NLAYERS; ++i) {
        const size_t wo = (size_t)i * HDIM * HDIM;
        pack_t_k<<<256, blk, 0, stream>>>(wc_W2 + wo, W2t + i * 65536, 256);
        pack_t_k<<<256, blk, 0, stream>>>(wc_W1 + wo, W1t + i * 65536, 256);
        pack_t_k<<<256, blk, 0, stream>>>(wc_W3 + wo, W3t + i * 65536, 256);
        pack_cat_k<<<512, blk, 0, stream>>>(sc_Wn + wo, sc_Wr + wo, WtC + i * 131072);
    }

    // ---- lin0 K-split: P0 = esm[:, :640]@WA, P1 = esm[:, 640:]@WB (concurrent)
    mgemm_k<SRC_F32Y, EPI_PART, 10><<<dim3(gemmGrid, 2), blk, 0, stream>>>(
        esm, FIN, nullptr, nullptr, nullptr, nullptr, lin0tA, lin0tB,
        nullptr, nullptr, aggf, HDIM, part1, nullptr, nullptr);
    // xh = f16(P0 + P1 + b)
    combine_k<<<waveGrid, blk, 0, stream>>>(aggf, part1, lin0_b, xh);

    for (int i = 0; i < NLAYERS; ++i) {
        const size_t bo = (size_t)i * HDIM;
        const f16* w2 = W2t + i * 65536;
        const f16* w1 = W1t + i * 65536;
        const f16* w3 = W3t + i * 65536;
        const f16* wc = WtC + i * 131072;

        // fused y-pair: y0: hnb = f16(xm@W2 + b2); y1: xw1h = f16(xm@W1 + b1)
        if (i == 0) {
            mgemm_k<SRC_H, EPI_W2W1H, 4><<<dim3(gemmGrid, 2), blk, 0, stream>>>(
                nullptr, 0, xh, nullptr, nullptr, nullptr, w2, w1,
                wc_b2 + bo, wc_b1 + bo, nullptr, 0, nullptr, hnb, xw1h);
        } else {
            mgemm_k<SRC_MULH, EPI_W2W1H, 4><<<dim3(gemmGrid, 2), blk, 0, stream>>>(
                nullptr, 0, xh, maskh, nullptr, nullptr, w2, w1,
                wc_b2 + bo, wc_b1 + bo, nullptr, 0, nullptr, hnb, xw1h);
        }
        // agg = segment_sum(h_nb[src], dst)   (f32 accum)
        gather_h_k<<<waveGrid, blk, 0, stream>>>(hnb, csr, starts, aggf);
        // mask = sigmoid(relu(agg + xw1h)@W3 + b3); xg = xh*mask  (both f16)
        mgemm_k<SRC_ADDRELU_H, EPI_MASKXG, 4><<<gemmGrid, blk, 0, stream>>>(
            aggf, HDIM, nullptr, xw1h, nullptr, xh, w3, w3,
            wc_b3 + bo, nullptr, nullptr, 0, nullptr, hnb, maskh);
        // agg2 = segment_sum(xg[src], dst)
        gather_g_k<<<waveGrid, blk, 0, stream>>>(hnb, csr, starts, agg2);
        // x_new = relu([agg2 | xh]@[Wn;Wr] + bn) -> d_out slice i (+ xh f16)
        mgemm_k<SRC_CATH, EPI_CATH, 8><<<gemmGrid, blk, 0, stream>>>(
            nullptr, 0, agg2, nullptr, xh, nullptr, wc, wc,
            sc_bn + bo, nullptr, out + (size_t)i * HDIM, LDOUT, nullptr, xh, nullptr);
    }

    // node_mask: all true
    const size_t maskOff = (size_t)NNODES * LDOUT;
    fill1_k<<<(NNODES + 255) / 256, blk, 0, stream>>>(out + maskOff, NNODES);
}